// Round 6
// baseline (1023.603 us; speedup 1.0000x reference)
//
#include <hip/hip_runtime.h>
#include <hip/hip_fp16.h>

#define B_ 128
#define T_ 64
#define I_ 128
#define H_ 256
#define UF 6
#define EPSF 1e-8f

typedef _Float16 f16x2 __attribute__((ext_vector_type(2)));
union H2U { __half2 h; f16x2 v; unsigned u; };

static __device__ __forceinline__ float rcpf(float x) { return __builtin_amdgcn_rcpf(x); }

// packed-fp16 dual gate: 2 sigmoids + f32 dot-accumulate into NM/DN
#define GATE2(VW, AK, BK, WK, NM, DN) {                        \
    H2U v2_; v2_.u = (VW);                                     \
    H2U av_; av_.u = (AK);                                     \
    H2U bv_; bv_.u = (BK);                                     \
    __half2 z_ = __hfma2(av_.h, v2_.h, bv_.h);                 \
    __half2 e_ = h2exp2(z_);                                   \
    __half2 s_ = __hadd2(e_, __float2half2_rn(1.0f));          \
    H2U rv_; rv_.h = h2rcp(s_);                                \
    H2U ws_; ws_.u = (WK);                                     \
    H2U wa_; wa_.u = ws_.u & 0x7fff7fffu;                      \
    NM = __builtin_amdgcn_fdot2(ws_.v, rv_.v, NM, false);      \
    DN = __builtin_amdgcn_fdot2(wa_.v, rv_.v, DN, false);      \
}

// ---------------- K0: pack params to pair-packed fp16, zero the exchange tags.
// A = -sigma*log2e, B = sigma*mu*log2e, W = w*erev (|W| = w since erev = +-1).
__global__ __launch_bounds__(256) void pack_params(
    const float* __restrict__ smu, const float* __restrict__ ssig,
    const float* __restrict__ sw,  const float* __restrict__ serev,
    const float* __restrict__ imu, const float* __restrict__ isig,
    const float* __restrict__ iw,  const float* __restrict__ ierev,
    uint2* __restrict__ ABp, unsigned* __restrict__ Wp,
    uint2* __restrict__ SAB, unsigned* __restrict__ SW,
    unsigned* __restrict__ Vg4)
{
    const float L2E = 1.4426950408889634f;
    int idx = blockIdx.x * 256 + threadIdx.x;   // 32768 = 128 x 256
    int r = idx >> 8, jg = idx & 255;
    {   // internal pair r = (2r, 2r+1)
        int i0 = 2 * r, i1 = i0 + 1;
        unsigned a0 = __half_as_ushort(__float2half_rn(-isig[i0 * H_ + jg] * L2E));
        unsigned a1 = __half_as_ushort(__float2half_rn(-isig[i1 * H_ + jg] * L2E));
        unsigned b0 = __half_as_ushort(__float2half_rn(isig[i0 * H_ + jg] * imu[i0 * H_ + jg] * L2E));
        unsigned b1 = __half_as_ushort(__float2half_rn(isig[i1 * H_ + jg] * imu[i1 * H_ + jg] * L2E));
        ABp[idx] = make_uint2(a0 | (a1 << 16), b0 | (b1 << 16));
        unsigned w0 = __half_as_ushort(__float2half_rn(iw[i0 * H_ + jg] * ierev[i0 * H_ + jg]));
        unsigned w1 = __half_as_ushort(__float2half_rn(iw[i1 * H_ + jg] * ierev[i1 * H_ + jg]));
        Wp[idx] = w0 | (w1 << 16);
    }
    if (idx < 64 * H_) {    // sensing pair r = (2r, 2r+1), r < 64
        int i0 = 2 * r, i1 = i0 + 1;
        unsigned a0 = __half_as_ushort(__float2half_rn(-ssig[i0 * H_ + jg] * L2E));
        unsigned a1 = __half_as_ushort(__float2half_rn(-ssig[i1 * H_ + jg] * L2E));
        unsigned b0 = __half_as_ushort(__float2half_rn(ssig[i0 * H_ + jg] * smu[i0 * H_ + jg] * L2E));
        unsigned b1 = __half_as_ushort(__float2half_rn(ssig[i1 * H_ + jg] * smu[i1 * H_ + jg] * L2E));
        SAB[idx] = make_uint2(a0 | (a1 << 16), b0 | (b1 << 16));
        unsigned w0 = __half_as_ushort(__float2half_rn(sw[i0 * H_ + jg] * serev[i0 * H_ + jg]));
        unsigned w1 = __half_as_ushort(__float2half_rn(sw[i1 * H_ + jg] * serev[i1 * H_ + jg]));
        SW[idx] = w0 | (w1 << 16);
    }
    Vg4[idx] = 0u;              // zero exchange tags (2*B*H = 65536 words)
    Vg4[idx + 32768] = 0u;
}

// ---------------- K1: recurrent LTC. 2 blocks per batch (j-half each), 1 block/CU,
// all 256 blocks co-resident. Lane map tid = j*8 + c so the 8 partials per neuron
// reduce via shfl_xor in-wave. All params register-cached as packed fp16.
// waves_per_eu(4,4): exactly 16 waves/CU -> VGPR budget 128, prevents the
// 64-VGPR squeeze that spilled the param arrays to scratch (R4: 30 GB FETCH).
// V exchanged cross-block via self-tagged relaxed agent atomics, double-buffered;
// the peer load is ISSUED before phase A so its L3 RT hides under gate compute.
__global__ __launch_bounds__(1024)
__attribute__((amdgpu_waves_per_eu(4, 4)))
void ltc_rec(
    const float* __restrict__ x, const float* __restrict__ in_w, const float* __restrict__ in_b,
    const uint2* __restrict__ ABp, const unsigned* __restrict__ Wp,
    const uint2* __restrict__ SAB, const unsigned* __restrict__ SW,
    const float* __restrict__ vleak, const float* __restrict__ gleak, const float* __restrict__ cm,
    const float* __restrict__ out_w, const float* __restrict__ out_b,
    unsigned* __restrict__ Vg4,
    float* __restrict__ out, float* __restrict__ hT)
{
    __shared__ __align__(16) unsigned V2u[H_ / 2];   // packed fp16 V pairs (full H)
    __shared__ __align__(16) unsigned xs2[I_ / 2];   // packed fp16 xm pairs

    const int bx  = blockIdx.x;
    const int b   = bx & 127;
    const int jh  = bx >> 7;                  // own j-half
    const int tid = threadIdx.x;
    const int c   = tid & 7;                  // i-chunk (low bits -> wave shfl reduce)
    const int j   = tid >> 3;                 // 0..127 local neuron
    const int jg  = (jh << 7) + j;
    const int pjbase = ((jh ^ 1) << 7);
    const int BH  = B_ * H_;

    // ---- register-cache params (packed fp16 pairs)
    unsigned ra[16], rb[16], rw[16];          // internal: 8 own + 8 peer pairs
    unsigned sa[8], sb[8], sw8[8];            // sensing: 8 pairs
    {
        const int po = (jh << 6) + (c << 3);
        const int pp = ((jh ^ 1) << 6) + (c << 3);
        const int ps = (c << 3);
        #pragma unroll
        for (int k = 0; k < 8; ++k) {
            uint2 u0 = ABp[((po + k) << 8) + jg];
            ra[k] = u0.x; rb[k] = u0.y; rw[k] = Wp[((po + k) << 8) + jg];
            uint2 u1 = ABp[((pp + k) << 8) + jg];
            ra[8 + k] = u1.x; rb[8 + k] = u1.y; rw[8 + k] = Wp[((pp + k) << 8) + jg];
            uint2 u2 = SAB[((ps + k) << 8) + jg];
            sa[k] = u2.x; sb[k] = u2.y; sw8[k] = SW[((ps + k) << 8) + jg];
        }
    }

    const float cmt  = cm[jg] * (float)UF;
    const float gl   = gleak[jg];
    const float glvl = gl * vleak[jg];
    const float dc   = cmt + gl + EPSF;
    const float owj  = out_w[jg], obj = out_b[jg];
    float iw0 = 0.f, iw1 = 0.f, ib0 = 0.f, ib1 = 0.f;
    if (tid < 64) { iw0 = in_w[2 * tid]; iw1 = in_w[2 * tid + 1];
                    ib0 = in_b[2 * tid]; ib1 = in_b[2 * tid + 1]; }
    if (tid < H_ / 2) V2u[tid] = 0u;
    float vreg = 0.f;

    const float* xrow = x + (size_t)b * (T_ * I_);

    for (int t = 0; t < T_; ++t) {
        if (tid < 64) {
            float2 xv = *reinterpret_cast<const float2*>(xrow + t * I_ + 2 * tid);
            __half2 hh = __floats2half2_rn(fmaf(xv.x, iw0, ib0), fmaf(xv.y, iw1, ib1));
            H2U u; u.h = hh; xs2[tid] = u.u;
        }
        __syncthreads();   // xs2 ready (and V2u init at t==0)

        // ---- sensing partials (packed fp16), kept in regs for all 6 unfolds
        float qsn = 0.f, qsd = 0.f;
        {
            const uint4 xa = *reinterpret_cast<const uint4*>(xs2 + (c << 3));
            const uint4 xb = *reinterpret_cast<const uint4*>(xs2 + (c << 3) + 4);
            GATE2(xa.x, sa[0], sb[0], sw8[0], qsn, qsd);
            GATE2(xa.y, sa[1], sb[1], sw8[1], qsn, qsd);
            GATE2(xa.z, sa[2], sb[2], sw8[2], qsn, qsd);
            GATE2(xa.w, sa[3], sb[3], sw8[3], qsn, qsd);
            GATE2(xb.x, sa[4], sb[4], sw8[4], qsn, qsd);
            GATE2(xb.y, sa[5], sb[5], sw8[5], qsn, qsd);
            GATE2(xb.z, sa[6], sb[6], sw8[6], qsn, qsd);
            GATE2(xb.w, sa[7], sb[7], sw8[7], qsn, qsd);
        }

        for (int u = 0; u < UF; ++u) {
            const int p = t * UF + u + 1;
            float nm = qsn, dn = qsd;

            // ---- prefetch peer V(p-1): issue load now, check after phase A
            unsigned pv = 0; const unsigned* src = nullptr; unsigned want = 0;
            if (p > 1 && tid < 128) {
                want = (unsigned)(p - 1);
                src = Vg4 + (size_t)(want & 1) * BH + (b << 8) + pjbase + tid;
                pv = __hip_atomic_load(src, __ATOMIC_RELAXED, __HIP_MEMORY_SCOPE_AGENT);
            }

            // ---- phase A: own-half i's (L3 RT of the prefetch hides under this)
            {
                const int vb = (jh << 6) + (c << 3);
                const uint4 va = *reinterpret_cast<const uint4*>(V2u + vb);
                const uint4 vb4 = *reinterpret_cast<const uint4*>(V2u + vb + 4);
                GATE2(va.x,  ra[0], rb[0], rw[0], nm, dn);
                GATE2(va.y,  ra[1], rb[1], rw[1], nm, dn);
                GATE2(va.z,  ra[2], rb[2], rw[2], nm, dn);
                GATE2(va.w,  ra[3], rb[3], rw[3], nm, dn);
                GATE2(vb4.x, ra[4], rb[4], rw[4], nm, dn);
                GATE2(vb4.y, ra[5], rb[5], rw[5], nm, dn);
                GATE2(vb4.z, ra[6], rb[6], rw[6], nm, dn);
                GATE2(vb4.w, ra[7], rb[7], rw[7], nm, dn);
            }

            // ---- waves 0-1: finish poll, pack into peer V2u region
            if (p > 1 && tid < 128) {
                while ((pv >> 16) != want)
                    pv = __hip_atomic_load(src, __ATOMIC_RELAXED, __HIP_MEMORY_SCOPE_AGENT);
                unsigned hv = pv & 0xffffu;
                unsigned hv1 = (unsigned)__shfl_down((int)hv, 1);
                if (!(tid & 1)) V2u[(pjbase >> 1) + (tid >> 1)] = hv | (hv1 << 16);
            }
            __syncthreads();   // peer V2u ready

            // ---- phase B: peer-half i's
            {
                const int vb = ((jh ^ 1) << 6) + (c << 3);
                const uint4 va = *reinterpret_cast<const uint4*>(V2u + vb);
                const uint4 vb4 = *reinterpret_cast<const uint4*>(V2u + vb + 4);
                GATE2(va.x,  ra[8],  rb[8],  rw[8],  nm, dn);
                GATE2(va.y,  ra[9],  rb[9],  rw[9],  nm, dn);
                GATE2(va.z,  ra[10], rb[10], rw[10], nm, dn);
                GATE2(va.w,  ra[11], rb[11], rw[11], nm, dn);
                GATE2(vb4.x, ra[12], rb[12], rw[12], nm, dn);
                GATE2(vb4.y, ra[13], rb[13], rw[13], nm, dn);
                GATE2(vb4.z, ra[14], rb[14], rw[14], nm, dn);
                GATE2(vb4.w, ra[15], rb[15], rw[15], nm, dn);
            }

            // ---- in-wave reduce over c (8 lanes per neuron)
            nm += __shfl_xor(nm, 1); dn += __shfl_xor(dn, 1);
            nm += __shfl_xor(nm, 2); dn += __shfl_xor(dn, 2);
            nm += __shfl_xor(nm, 4); dn += __shfl_xor(dn, 4);

            // ---- update (all lanes redundantly), publish + own V2u write (c==0)
            float Vn = (fmaf(vreg, cmt, glvl) + nm) * rcpf(dn + dc);
            vreg = Vn;
            unsigned h0 = __half_as_ushort(__float2half_rn(Vn));
            if (c == 0)
                __hip_atomic_store(Vg4 + (size_t)(p & 1) * BH + (b << 8) + jg,
                                   ((unsigned)p << 16) | h0,
                                   __ATOMIC_RELAXED, __HIP_MEMORY_SCOPE_AGENT);
            unsigned h1 = (unsigned)__shfl_down((int)h0, 8);
            if (c == 0 && !(j & 1)) V2u[jg >> 1] = h0 | (h1 << 16);
            __syncthreads();   // own V2u ready for next phase A
        }

        if (c == 0) out[((size_t)b * T_ + t) * H_ + jg] = fmaf(vreg, owj, obj);
    }
    if (c == 0) hT[(b << 8) + jg] = vreg;
}

extern "C" void kernel_launch(void* const* d_in, const int* in_sizes, int n_in,
                              void* d_out, int out_size, void* d_ws, size_t ws_size,
                              hipStream_t stream) {
    const float* x     = (const float*)d_in[0];
    const float* in_w  = (const float*)d_in[1];
    const float* in_b  = (const float*)d_in[2];
    const float* smu   = (const float*)d_in[3];
    const float* ssig  = (const float*)d_in[4];
    const float* sw    = (const float*)d_in[5];
    const float* serev = (const float*)d_in[6];
    const float* imu   = (const float*)d_in[7];
    const float* isig  = (const float*)d_in[8];
    const float* iw    = (const float*)d_in[9];
    const float* ierev = (const float*)d_in[10];
    const float* vleak = (const float*)d_in[11];
    const float* gleak = (const float*)d_in[12];
    const float* cmv   = (const float*)d_in[13];
    const float* ow    = (const float*)d_in[14];
    const float* ob    = (const float*)d_in[15];

    float* out = (float*)d_out;                 // [B, T, H]
    float* hT  = out + (size_t)B_ * T_ * H_;    // [B, H]

    char* w = (char*)d_ws;
    uint2*    ABp = (uint2*)(w);                    // 256 KB [pair][jg]
    unsigned* Wp  = (unsigned*)(w + (256 << 10));   // 128 KB [pair][jg]
    uint2*    SAB = (uint2*)(w + (384 << 10));      // 128 KB [pair][jg]
    unsigned* SW  = (unsigned*)(w + (512 << 10));   //  64 KB [pair][jg]
    unsigned* Vg4 = (unsigned*)(w + (576 << 10));   // 256 KB [2][B][H] tag|fp16

    pack_params<<<dim3(128), dim3(256), 0, stream>>>(
        smu, ssig, sw, serev, imu, isig, iw, ierev, ABp, Wp, SAB, SW, Vg4);

    ltc_rec<<<dim3(256), dim3(1024), 0, stream>>>(
        x, in_w, in_b, ABp, Wp, SAB, SW, vleak, gleak, cmv, ow, ob,
        Vg4, out, hT);
}